// Round 20
// baseline (89.788 us; speedup 1.0000x reference)
//
#include <hip/hip_runtime.h>
#include <hip/hip_bf16.h>

typedef __bf16 bf16x8 __attribute__((ext_vector_type(8)));
typedef __bf16 bf16x4 __attribute__((ext_vector_type(4)));
typedef float  f32x4  __attribute__((ext_vector_type(4)));

constexpr int kNHRZ = 2048, kBATCH = 128, kNU = 64, kNY = 64, kNH = 256, kH = 128;
constexpr int kCHUNK = 256, kNCHUNK = kNHRZ / kCHUNK;  // 8 chunks of 256 steps
constexpr int kTS = 16, kBT = 2, kM = kTS * kBT;       // 32 (b,t) rows per subtile
constexpr int kNSUB = kCHUNK / kTS;                    // 16 subtiles per chunk

// LDS strides (elements)
constexpr int U_STR  = 72;   // bf16, 144 B rows
constexpr int BT_STR = 36;   // Bu_T[h][b*16+t], 72 B rows (R14-proven)
constexpr int X_STR  = 264;  // bf16, 528 B rows

constexpr int OFF_U  = 0;                            // Us dbuf: 2*32*72*2 = 9216 B
constexpr int OFF_BU = OFF_U + 2 * kM * U_STR * 2;   // Bu_T: 256*36*2 = 18432 B
constexpr int OFF_X  = OFF_BU + kNH * BT_STR * 2;    // 27648
constexpr int SMEM1  = OFF_X + kM * X_STR * 2;       // pass1: 44544 B
constexpr int SMEM2  = 2 * kM * X_STR * 2;           // pass2: Xs dbuf only, 33792 B

__device__ inline bf16x8 pack8(float4 a, float4 b) {
    bf16x8 v;
    v[0] = (__bf16)a.x; v[1] = (__bf16)a.y; v[2] = (__bf16)a.z; v[3] = (__bf16)a.w;
    v[4] = (__bf16)b.x; v[5] = (__bf16)b.y; v[6] = (__bf16)b.z; v[7] = (__bf16)b.w;
    return v;
}

// ---------------------------------------------------------------------------
// Pass 1 — local scan (zero init) + Y_local projection + chunk ends.
// Exactly R18's verified FINAL path with x-init = 0 and an ends-write
// epilogue. By linearity x_t = x_t^local + lambda^(tl+1) * x_start; pass 2
// adds the correction. This removes the duplicated stage+GEMM1+scan that the
// old two-pass structure paid (17.2 of 25.8 GF).
// Block = (chunk c, batch pair), 256 threads = 4 waves, 16 subtiles.
// Wave w owns modes [w*32, w*32+32): 4 nt tiles = real lo/hi + imag lo/hi
// -> Bf [2][4] (32 regs) and BuT store/read same-wave (no GEMM1->scan bar).
// MFMA 16x16x32 bf16: A row=lane&15, k=(lane>>4)*8+j; C/D col=lane&15,
// row=(lane>>4)*4+i (4 contiguous t per lane -> b64 BuT stores).
// NOTE: __launch_bounds__(256,2) — tighter bounds spill fragments (R4/R11).
// ---------------------------------------------------------------------------
__global__ __launch_bounds__(256, 2) void scan_local(
    const float* __restrict__ U,      // (NHRZ, BATCH, NU)
    const float* __restrict__ lre,    // (H,)
    const float* __restrict__ lim,    // (H,)
    const float* __restrict__ Bmat,   // (NH, NU)
    const float* __restrict__ Wx2y,   // (NY, NH)
    const float* __restrict__ bx2y,   // (NY,)
    float* __restrict__ ends,         // (NCHUNK, BATCH, NH)
    float* __restrict__ out)          // (NHRZ+1, BATCH, NY)
{
    extern __shared__ char smem[];
    __bf16* Us  = (__bf16*)(smem + OFF_U);    // [2][kM][U_STR], rows b-major
    __bf16* BuT = (__bf16*)(smem + OFF_BU);   // [kNH][BT_STR]
    __bf16* Xs  = (__bf16*)(smem + OFF_X);    // [kM][X_STR]

    const int tid  = threadIdx.x;
    const int lane = tid & 63;
    const int w    = tid >> 6;            // wave 0..3
    const int lw   = lane & 15;
    const int lg   = lane >> 4;
    const int blk  = blockIdx.x;
    const int c    = blk >> 6;            // chunk 0..7
    const int bp   = blk & 63;            // batch pair 0..63
    const int bglob = bp * 2;
    const int t0   = c * kCHUNK;

    // --- B fragments: wave w's 4 tiles (real lo/hi + imag lo/hi), nf folded
    bf16x8 Bf[2][4];
#pragma unroll
    for (int nt = 0; nt < 4; ++nt) {
        const int hre = w * 32 + (nt & 1) * 16 + lw;
        const int h   = hre + (nt >> 1) * kH;
        const float ab = fabsf(lre[hre]);
        const float nf = sqrtf(fmaxf(0.0f, 1.0f - expf(-2.0f * ab)));
#pragma unroll
        for (int ks = 0; ks < 2; ++ks) {
            const float* p = Bmat + h * kNU + ks * 32 + lg * 8;
            float4 f0 = ((const float4*)p)[0];
            float4 f1 = ((const float4*)p)[1];
            f0.x *= nf; f0.y *= nf; f0.z *= nf; f0.w *= nf;
            f1.x *= nf; f1.y *= nf; f1.z *= nf; f1.w *= nf;
            Bf[ks][nt] = pack8(f0, f1);
        }
    }

    // --- W fragments + bias
    bf16x8 Wf[8][2];
    float  bias[2];
#pragma unroll
    for (int nt = 0; nt < 2; ++nt) {
        const int y = (w >> 1) * 32 + nt * 16 + lw;
        bias[nt] = bx2y[y];
#pragma unroll
        for (int ks = 0; ks < 8; ++ks) {
            const float* p = Wx2y + y * kNH + ks * 32 + lg * 8;
            Wf[ks][nt] = pack8(((const float4*)p)[0], ((const float4*)p)[1]);
        }
    }

    // --- scan state (ZERO init — local scan) : hm = w*32+(lane&31), bl=lane>>5
    const int hm = w * 32 + (lane & 31);
    const int bl = lane >> 5;
    float lr, li;
    {
        const float ab = fabsf(lre[hm]);
        const float r  = expf(-ab);
        const float th = 1.5707963267948966f * lim[hm];
        lr = r * cosf(th);
        li = r * sinf(th);
    }
    float x1 = 0.0f, x2 = 0.0f;

    // U staging map: thread -> (row sm = b*16 + t, q = tid&7)
    const int sm = tid >> 3, sq = tid & 7;
    const int st_t = sm & 15, st_b = sm >> 4;
    const float* uptr0 =
        U + ((size_t)(t0 + st_t) * kBATCH + (bglob + st_b)) * kNU + sq * 8;

    float4 u0 = ((const float4*)uptr0)[0];
    float4 u1 = ((const float4*)uptr0)[1];

#pragma unroll 1
    for (int s = 0; s < kNSUB; ++s) {
        __bf16* Uc = Us + (s & 1) * (kM * U_STR);

        *(bf16x8*)&Uc[sm * U_STR + sq * 8] = pack8(u0, u1);
        __syncthreads();  // barB: Us[cur] staged

        // ---- GEMM1 -> BuT (b64, wave-local)
        {
            f32x4 acc[2][4] = {};
#pragma unroll
            for (int ks = 0; ks < 2; ++ks) {
                bf16x8 a0 = *(const bf16x8*)&Uc[(lw)      * U_STR + ks * 32 + lg * 8];
                bf16x8 a1 = *(const bf16x8*)&Uc[(16 + lw) * U_STR + ks * 32 + lg * 8];
#pragma unroll
                for (int nt = 0; nt < 4; ++nt) {
                    acc[0][nt] = __builtin_amdgcn_mfma_f32_16x16x32_bf16(a0, Bf[ks][nt], acc[0][nt], 0, 0, 0);
                    acc[1][nt] = __builtin_amdgcn_mfma_f32_16x16x32_bf16(a1, Bf[ks][nt], acc[1][nt], 0, 0, 0);
                }
            }
#pragma unroll
            for (int mt = 0; mt < 2; ++mt)
#pragma unroll
                for (int nt = 0; nt < 4; ++nt) {
                    const int h = w * 32 + (nt & 1) * 16 + lw + (nt >> 1) * kH;
                    bf16x4 v;
                    v[0] = (__bf16)acc[mt][nt][0]; v[1] = (__bf16)acc[mt][nt][1];
                    v[2] = (__bf16)acc[mt][nt][2]; v[3] = (__bf16)acc[mt][nt][3];
                    *(bf16x4*)&BuT[h * BT_STR + mt * 16 + lg * 4] = v;
                }
        }
        // (no barrier: BuT producer == consumer wave)

        // ---- scan 16 steps from registers; write local X
        {
            bf16x4 qr[4], qi[4];
#pragma unroll
            for (int k = 0; k < 4; ++k) {
                qr[k] = *(const bf16x4*)&BuT[hm * BT_STR + bl * 16 + k * 4];
                qi[k] = *(const bf16x4*)&BuT[(hm + kH) * BT_STR + bl * 16 + k * 4];
            }
#pragma unroll
            for (int t = 0; t < kTS; ++t) {
                const float bu1 = (float)qr[t >> 2][t & 3];
                const float bu2 = (float)qi[t >> 2][t & 3];
                const float n1 = fmaf(lr, x1, fmaf(-li, x2, bu1));
                const float n2 = fmaf(li, x1, fmaf(lr, x2, bu2));
                x1 = n1; x2 = n2;
                const int m = bl * 16 + t;
                Xs[m * X_STR + hm]      = (__bf16)x1;
                Xs[m * X_STR + kH + hm] = (__bf16)x2;
            }
        }

        __syncthreads();  // barC: Xs ready
        // ---- prefetch next subtile (crosses no barrier before use)
        if (s + 1 < kNSUB) {
            const float* p = uptr0 + (size_t)(s + 1) * kTS * kBATCH * kNU;
            u0 = ((const float4*)p)[0];
            u1 = ((const float4*)p)[1];
        }
        // ---- GEMM2: batch tile mtY=w&1 (rows = pure t), N=32, K=256
        f32x4 acc2[2] = {};
        const int mtY = w & 1;
#pragma unroll
        for (int ks = 0; ks < 8; ++ks) {
            bf16x8 a = *(const bf16x8*)&Xs[(mtY * 16 + lw) * X_STR + ks * 32 + lg * 8];
            acc2[0] = __builtin_amdgcn_mfma_f32_16x16x32_bf16(a, Wf[ks][0], acc2[0], 0, 0, 0);
            acc2[1] = __builtin_amdgcn_mfma_f32_16x16x32_bf16(a, Wf[ks][1], acc2[1], 0, 0, 0);
        }
#pragma unroll
        for (int i = 0; i < 4; ++i) {
            const int t = t0 + s * kTS + lg * 4 + i;
            float* orow = out + ((size_t)(1 + t) * kBATCH + bglob + mtY) * kNY +
                          (w >> 1) * 32 + lw;
#pragma unroll
            for (int nt = 0; nt < 2; ++nt)
                orow[nt * 16] = acc2[nt][i] + bias[nt];
        }
    }

    // ---- epilogue: chunk-local end state (zero-init scan)
    {
        const size_t eb = ((size_t)c * kBATCH + bglob + bl) * kNH;
        ends[eb + hm]      = x1;
        ends[eb + hm + kH] = x2;
    }
}

// ---------------------------------------------------------------------------
// Pass 2 — correction: Y += W (lambda^(tl+1) ⊙ x_start). No U, no GEMM1.
// Per thread: c <- starts, then c <- lambda*c per step; states -> Xs (dbuf);
// GEMM2; out +=. One barrier/subtile; Xs dbuf makes WAR safe (compiler
// drains lgkm before each s_barrier, so GEMM2(s-1) reads retired before any
// wave's writes(s+1) to the same buffer).
// ---------------------------------------------------------------------------
__global__ __launch_bounds__(256, 2) void scan_corr(
    const float* __restrict__ lre,    // (H,)
    const float* __restrict__ lim,    // (H,)
    const float* __restrict__ Wx2y,   // (NY, NH)
    const float* __restrict__ starts, // (NCHUNK, BATCH, NH)
    float* __restrict__ out)          // (NHRZ+1, BATCH, NY)
{
    extern __shared__ char smem[];
    __bf16* Xs = (__bf16*)smem;       // [2][kM][X_STR]

    const int tid  = threadIdx.x;
    const int lane = tid & 63;
    const int w    = tid >> 6;
    const int lw   = lane & 15;
    const int lg   = lane >> 4;
    const int blk  = blockIdx.x;
    const int c    = blk >> 6;
    const int bp   = blk & 63;
    const int bglob = bp * 2;
    const int t0   = c * kCHUNK;

    // --- W fragments (no bias — pass 1 added it)
    bf16x8 Wf[8][2];
#pragma unroll
    for (int nt = 0; nt < 2; ++nt) {
        const int y = (w >> 1) * 32 + nt * 16 + lw;
#pragma unroll
        for (int ks = 0; ks < 8; ++ks) {
            const float* p = Wx2y + y * kNH + ks * 32 + lg * 8;
            Wf[ks][nt] = pack8(((const float4*)p)[0], ((const float4*)p)[1]);
        }
    }

    // --- rotation state from starts
    const int hm = w * 32 + (lane & 31);
    const int bl = lane >> 5;
    float lr, li;
    {
        const float ab = fabsf(lre[hm]);
        const float r  = expf(-ab);
        const float th = 1.5707963267948966f * lim[hm];
        lr = r * cosf(th);
        li = r * sinf(th);
    }
    float c1, c2;
    {
        const size_t sb = ((size_t)c * kBATCH + bglob + bl) * kNH;
        c1 = starts[sb + hm];
        c2 = starts[sb + hm + kH];
    }

#pragma unroll 1
    for (int s = 0; s < kNSUB; ++s) {
        __bf16* Xc = Xs + (s & 1) * (kM * X_STR);

        // ---- rotation-only scan: c <- lambda*c, write states
#pragma unroll
        for (int t = 0; t < kTS; ++t) {
            const float n1 = fmaf(lr, c1, -li * c2);
            const float n2 = fmaf(li, c1,  lr * c2);
            c1 = n1; c2 = n2;
            const int m = bl * 16 + t;
            Xc[m * X_STR + hm]      = (__bf16)c1;
            Xc[m * X_STR + kH + hm] = (__bf16)c2;
        }

        __syncthreads();  // Xc ready (cross-wave RAW)

        // ---- GEMM2 + out +=
        f32x4 acc2[2] = {};
        const int mtY = w & 1;
#pragma unroll
        for (int ks = 0; ks < 8; ++ks) {
            bf16x8 a = *(const bf16x8*)&Xc[(mtY * 16 + lw) * X_STR + ks * 32 + lg * 8];
            acc2[0] = __builtin_amdgcn_mfma_f32_16x16x32_bf16(a, Wf[ks][0], acc2[0], 0, 0, 0);
            acc2[1] = __builtin_amdgcn_mfma_f32_16x16x32_bf16(a, Wf[ks][1], acc2[1], 0, 0, 0);
        }
#pragma unroll
        for (int i = 0; i < 4; ++i) {
            const int t = t0 + s * kTS + lg * 4 + i;
            float* orow = out + ((size_t)(1 + t) * kBATCH + bglob + mtY) * kNY +
                          (w >> 1) * 32 + lw;
#pragma unroll
            for (int nt = 0; nt < 2; ++nt)
                orow[nt * 16] += acc2[nt][i];
        }
    }
}

// ---------------------------------------------------------------------------
// Sequential combine over chunks + x0 computation. lambda^256 = 8 squarings.
// ---------------------------------------------------------------------------
__global__ __launch_bounds__(128) void combine_kernel(
    const float* __restrict__ y0, const float* __restrict__ Wy2x,
    const float* __restrict__ by2x, const float* __restrict__ lre,
    const float* __restrict__ lim, const float* __restrict__ ends,
    float* __restrict__ starts)
{
    const int b  = blockIdx.x;
    const int hm = threadIdx.x;

    const float ab = fabsf(lre[hm]);
    const float r  = expf(-ab);
    const float th = 1.5707963267948966f * lim[hm];
    float lr = r * cosf(th);
    float li = r * sinf(th);
    float pr = lr, pi = li;
#pragma unroll
    for (int k = 0; k < 8; ++k) {  // lambda^256
        const float nr = pr * pr - pi * pi;
        const float ni = 2.0f * pr * pi;
        pr = nr; pi = ni;
    }

    float s1 = by2x[hm];
    float s2 = by2x[hm + kH];
#pragma unroll 8
    for (int q = 0; q < kNY; ++q) {
        const float yv = y0[b * kNY + q];
        s1 = fmaf(Wy2x[hm * kNY + q], yv, s1);
        s2 = fmaf(Wy2x[(hm + kH) * kNY + q], yv, s2);
    }

    for (int c = 0; c < kNCHUNK; ++c) {
        const size_t base = ((size_t)c * kBATCH + b) * kNH;
        starts[base + hm]      = s1;
        starts[base + hm + kH] = s2;
        const float e1 = ends[base + hm];
        const float e2 = ends[base + hm + kH];
        const float n1 = fmaf(pr, s1, fmaf(-pi, s2, e1));
        const float n2 = fmaf(pi, s1, fmaf(pr, s2, e2));
        s1 = n1; s2 = n2;
    }
}

// Y row 0 = Wx2y @ x0 + bx2y  (x0 = starts[c=0])
__global__ __launch_bounds__(64) void y0_kernel(
    const float* __restrict__ starts, const float* __restrict__ Wx2y,
    const float* __restrict__ bx2y, float* __restrict__ out)
{
    const int b = blockIdx.x;
    const int y = threadIdx.x;
    const float* x0 = starts + (size_t)b * kNH;
    float acc = bx2y[y];
#pragma unroll 4
    for (int h = 0; h < kNH; h += 4) {
        float4 xv = *(const float4*)&x0[h];
        float4 wv = *(const float4*)&Wx2y[y * kNH + h];
        acc = fmaf(wv.x, xv.x, acc);
        acc = fmaf(wv.y, xv.y, acc);
        acc = fmaf(wv.z, xv.z, acc);
        acc = fmaf(wv.w, xv.w, acc);
    }
    out[(size_t)b * kNY + y] = acc;
}

extern "C" void kernel_launch(void* const* d_in, const int* in_sizes, int n_in,
                              void* d_out, int out_size, void* d_ws, size_t ws_size,
                              hipStream_t stream) {
    const float* y0   = (const float*)d_in[0];
    const float* U    = (const float*)d_in[1];
    const float* lre  = (const float*)d_in[2];
    const float* lim  = (const float*)d_in[3];
    const float* Bmat = (const float*)d_in[4];
    const float* Wy2x = (const float*)d_in[5];
    const float* by2x = (const float*)d_in[6];
    const float* Wx2y = (const float*)d_in[7];
    const float* bx2y = (const float*)d_in[8];
    float* out = (float*)d_out;

    float* ends   = (float*)d_ws;                          // 1 MB
    float* starts = ends + (size_t)kNCHUNK * kBATCH * kNH; // 1 MB

    const int grid = kNCHUNK * (kBATCH / kBT);  // 512 blocks

    scan_local<<<grid, 256, SMEM1, stream>>>(
        U, lre, lim, Bmat, Wx2y, bx2y, ends, out);
    combine_kernel<<<kBATCH, 128, 0, stream>>>(
        y0, Wy2x, by2x, lre, lim, ends, starts);
    y0_kernel<<<kBATCH, 64, 0, stream>>>(starts, Wx2y, bx2y, out);
    scan_corr<<<grid, 256, SMEM2, stream>>>(
        lre, lim, Wx2y, starts, out);
}

// Round 21
// 75.866 us; speedup vs baseline: 1.1835x; 1.1835x over previous
//
#include <hip/hip_runtime.h>
#include <hip/hip_bf16.h>

typedef __bf16 bf16x8 __attribute__((ext_vector_type(8)));
typedef __bf16 bf16x4 __attribute__((ext_vector_type(4)));
typedef float  f32x4  __attribute__((ext_vector_type(4)));

constexpr int kNHRZ = 2048, kBATCH = 128, kNU = 64, kNY = 64, kNH = 256, kH = 128;
constexpr int kCHUNK = 256, kNCHUNK = kNHRZ / kCHUNK;  // 8 chunks of 256 steps
constexpr int kTS = 16, kBT = 2, kM = kTS * kBT;       // 32 (b,t) rows per subtile
constexpr int kNSUB = kCHUNK / kTS;                    // 16 subtiles per chunk

// LDS strides (elements)
constexpr int U_STR  = 72;   // bf16, 144 B rows
constexpr int BT_STR = 36;   // Bu_T[h][b*16+t], 72 B rows (R14-proven)
constexpr int X_STR  = 264;  // bf16, 528 B rows

constexpr int OFF_U  = 0;                            // Us dbuf: 2*32*72*2 = 9216 B
constexpr int OFF_BU = OFF_U + 2 * kM * U_STR * 2;   // Bu_T: 256*36*2 = 18432 B
constexpr int OFF_X  = OFF_BU + kNH * BT_STR * 2;    // 27648
constexpr int SMEM1  = OFF_X;                        // pass1: 27648 B
constexpr int SMEM2  = OFF_X + kM * X_STR * 2;       // pass2: 44544 B

__device__ inline bf16x8 pack8(float4 a, float4 b) {
    bf16x8 v;
    v[0] = (__bf16)a.x; v[1] = (__bf16)a.y; v[2] = (__bf16)a.z; v[3] = (__bf16)a.w;
    v[4] = (__bf16)b.x; v[5] = (__bf16)b.y; v[6] = (__bf16)b.z; v[7] = (__bf16)b.w;
    return v;
}

// ---------------------------------------------------------------------------
// Fused per-chunk kernel — R18 (best verified: 77.1 us total) restored.
// R20 lesson: each pass is bound by rounds x per-round LATENCY, not work —
// removing GEMM1 from pass 2 (linearity split) made totals WORSE (89.8) by
// lengthening pass 1's chain while pass 2 still paid the per-round floor.
// Block = (chunk c, batch pair), 256 threads = 4 waves, 16 subtiles.
// Wave w owns modes [w*32, w*32+32): its 4 nt tiles are real lo/hi + imag
// lo/hi of its OWN modes -> Bf [2][4] (32 regs) AND BuT store/read same-wave.
// Scan lanes: hm = w*32 + (lane&31), bl = lane>>5.
// Pass1: ONE barrier/subtile. Pass2: +barC for Xs cross-wave RAW.
// Prefetch issued AFTER the subtile's last barrier (hipcc drains vmcnt(0)
// at every s_barrier — m97).
// MFMA 16x16x32 bf16: A row=lane&15, k=(lane>>4)*8+j; C/D col=lane&15,
// row=(lane>>4)*4+i (4 contiguous t per lane -> b64 BuT stores).
// NOTE: __launch_bounds__(256,2) — tighter bounds spill fragments (R4/R11);
// Bf[2][8] (64 regs) also spilled (R15). Keep Bf at 32 regs.
// ---------------------------------------------------------------------------
template <bool FINAL>
__global__ __launch_bounds__(256, 2) void scan_mfma(
    const float* __restrict__ U,      // (NHRZ, BATCH, NU)
    const float* __restrict__ lre,    // (H,)
    const float* __restrict__ lim,    // (H,)
    const float* __restrict__ Bmat,   // (NH, NU)
    const float* __restrict__ Wx2y,   // (NY, NH)   [FINAL]
    const float* __restrict__ bx2y,   // (NY,)      [FINAL]
    const float* __restrict__ starts, // (NCHUNK, BATCH, NH) [FINAL]
    float* __restrict__ ends,         // (NCHUNK, BATCH, NH) [!FINAL]
    float* __restrict__ out)          // (NHRZ+1, BATCH, NY) [FINAL]
{
    extern __shared__ char smem[];
    __bf16* Us  = (__bf16*)(smem + OFF_U);    // [2][kM][U_STR], rows b-major
    __bf16* BuT = (__bf16*)(smem + OFF_BU);   // [kNH][BT_STR]
    __bf16* Xs  = (__bf16*)(smem + OFF_X);    // [kM][X_STR]  (FINAL)

    const int tid  = threadIdx.x;
    const int lane = tid & 63;
    const int w    = tid >> 6;            // wave 0..3
    const int lw   = lane & 15;
    const int lg   = lane >> 4;
    const int blk  = blockIdx.x;
    const int c    = blk >> 6;            // chunk 0..7
    const int bp   = blk & 63;            // batch pair 0..63
    const int bglob = bp * 2;
    const int t0   = c * kCHUNK;

    // --- B fragments: wave w's 4 tiles = real lo/hi + imag lo/hi of its
    // 32 modes. h = w*32 + (nt&1)*16 + lw + (nt>>1)*128; nf folded.
    bf16x8 Bf[2][4];  // [ks][nt]
#pragma unroll
    for (int nt = 0; nt < 4; ++nt) {
        const int hre = w * 32 + (nt & 1) * 16 + lw;   // mode index
        const int h   = hre + (nt >> 1) * kH;          // +128 for imag tiles
        const float ab = fabsf(lre[hre]);
        const float nf = sqrtf(fmaxf(0.0f, 1.0f - expf(-2.0f * ab)));
#pragma unroll
        for (int ks = 0; ks < 2; ++ks) {
            const float* p = Bmat + h * kNU + ks * 32 + lg * 8;
            float4 f0 = ((const float4*)p)[0];
            float4 f1 = ((const float4*)p)[1];
            f0.x *= nf; f0.y *= nf; f0.z *= nf; f0.w *= nf;
            f1.x *= nf; f1.y *= nf; f1.z *= nf; f1.w *= nf;
            Bf[ks][nt] = pack8(f0, f1);
        }
    }

    // --- W fragments + bias in registers (FINAL)
    bf16x8 Wf[8][2];
    float  bias[2] = {0.f, 0.f};
    if constexpr (FINAL) {
#pragma unroll
        for (int nt = 0; nt < 2; ++nt) {
            const int y = (w >> 1) * 32 + nt * 16 + lw;
            bias[nt] = bx2y[y];
#pragma unroll
            for (int ks = 0; ks < 8; ++ks) {
                const float* p = Wx2y + y * kNH + ks * 32 + lg * 8;
                Wf[ks][nt] = pack8(((const float4*)p)[0], ((const float4*)p)[1]);
            }
        }
    }

    // --- per-thread scan constants / state: hm = w*32+(lane&31), bl = lane>>5
    const int hm = w * 32 + (lane & 31);
    const int bl = lane >> 5;
    float lr, li;
    {
        const float ab = fabsf(lre[hm]);
        const float r  = expf(-ab);
        const float th = 1.5707963267948966f * lim[hm];
        lr = r * cosf(th);
        li = r * sinf(th);
    }
    float x1, x2;
    if constexpr (FINAL) {
        const size_t sb = ((size_t)c * kBATCH + bglob + bl) * kNH;
        x1 = starts[sb + hm];
        x2 = starts[sb + hm + kH];
    } else {
        x1 = 0.0f; x2 = 0.0f;
    }

    // U staging map: thread -> (row sm = b*16 + t, q = tid&7), 32 B per thread
    const int sm = tid >> 3, sq = tid & 7;
    const int st_t = sm & 15, st_b = sm >> 4;
    const float* uptr0 =
        U + ((size_t)(t0 + st_t) * kBATCH + (bglob + st_b)) * kNU + sq * 8;

    // prefetch subtile 0
    float4 u0 = ((const float4*)uptr0)[0];
    float4 u1 = ((const float4*)uptr0)[1];

#pragma unroll 1
    for (int s = 0; s < kNSUB; ++s) {
        __bf16* Uc = Us + (s & 1) * (kM * U_STR);

        // ---- write staged U regs -> LDS[cur]
        *(bf16x8*)&Uc[sm * U_STR + sq * 8] = pack8(u0, u1);
        __syncthreads();  // barB: Us[cur] staged (cross-wave RAW + dbuf WAR)

        // ---- pass1 prefetch: issued right after barB, crosses no barrier
        if constexpr (!FINAL) {
            if (s + 1 < kNSUB) {
                const float* p = uptr0 + (size_t)(s + 1) * kTS * kBATCH * kNU;
                u0 = ((const float4*)p)[0];
                u1 = ((const float4*)p)[1];
            }
        }

        // ---- GEMM1: 2 batch tiles x wave's 4 nt tiles, K=64 -> BuT (b64)
        {
            f32x4 acc[2][4] = {};
#pragma unroll
            for (int ks = 0; ks < 2; ++ks) {
                bf16x8 a0 = *(const bf16x8*)&Uc[(lw)      * U_STR + ks * 32 + lg * 8];
                bf16x8 a1 = *(const bf16x8*)&Uc[(16 + lw) * U_STR + ks * 32 + lg * 8];
#pragma unroll
                for (int nt = 0; nt < 4; ++nt) {
                    acc[0][nt] = __builtin_amdgcn_mfma_f32_16x16x32_bf16(a0, Bf[ks][nt], acc[0][nt], 0, 0, 0);
                    acc[1][nt] = __builtin_amdgcn_mfma_f32_16x16x32_bf16(a1, Bf[ks][nt], acc[1][nt], 0, 0, 0);
                }
            }
            // acc[mt][nt][i]: row t = lg*4+i (contiguous), col h (wave-local)
#pragma unroll
            for (int mt = 0; mt < 2; ++mt)
#pragma unroll
                for (int nt = 0; nt < 4; ++nt) {
                    const int h = w * 32 + (nt & 1) * 16 + lw + (nt >> 1) * kH;
                    bf16x4 v;
                    v[0] = (__bf16)acc[mt][nt][0]; v[1] = (__bf16)acc[mt][nt][1];
                    v[2] = (__bf16)acc[mt][nt][2]; v[3] = (__bf16)acc[mt][nt][3];
                    *(bf16x4*)&BuT[h * BT_STR + mt * 16 + lg * 4] = v;
                }
        }
        // (no barrier: BuT rows hm/hm+128 produced by THIS wave; same-wave
        //  LDS ordering via lgkmcnt)

        // ---- scan, 16 steps from registers (8 x b64 vector loads, same-wave)
        {
            bf16x4 qr[4], qi[4];
#pragma unroll
            for (int k = 0; k < 4; ++k) {
                qr[k] = *(const bf16x4*)&BuT[hm * BT_STR + bl * 16 + k * 4];
                qi[k] = *(const bf16x4*)&BuT[(hm + kH) * BT_STR + bl * 16 + k * 4];
            }
#pragma unroll
            for (int t = 0; t < kTS; ++t) {
                const float bu1 = (float)qr[t >> 2][t & 3];
                const float bu2 = (float)qi[t >> 2][t & 3];
                const float n1 = fmaf(lr, x1, fmaf(-li, x2, bu1));
                const float n2 = fmaf(li, x1, fmaf(lr, x2, bu2));
                x1 = n1; x2 = n2;
                if constexpr (FINAL) {
                    const int m = bl * 16 + t;   // b-major rows, match GEMM2
                    Xs[m * X_STR + hm]      = (__bf16)x1;
                    Xs[m * X_STR + kH + hm] = (__bf16)x2;
                }
            }
        }

        if constexpr (FINAL) {
            __syncthreads();  // barC: Xs ready (cross-wave RAW)
            // ---- prefetch after the last barrier of the subtile
            if (s + 1 < kNSUB) {
                const float* p = uptr0 + (size_t)(s + 1) * kTS * kBATCH * kNU;
                u0 = ((const float4*)p)[0];
                u1 = ((const float4*)p)[1];
            }
            // ---- Y GEMM: batch tile mtY=w&1 (rows = pure t), N=32, K=256
            f32x4 acc2[2] = {};
            const int mtY = w & 1;
#pragma unroll
            for (int ks = 0; ks < 8; ++ks) {
                bf16x8 a = *(const bf16x8*)&Xs[(mtY * 16 + lw) * X_STR + ks * 32 + lg * 8];
                acc2[0] = __builtin_amdgcn_mfma_f32_16x16x32_bf16(a, Wf[ks][0], acc2[0], 0, 0, 0);
                acc2[1] = __builtin_amdgcn_mfma_f32_16x16x32_bf16(a, Wf[ks][1], acc2[1], 0, 0, 0);
            }
#pragma unroll
            for (int i = 0; i < 4; ++i) {
                const int t = t0 + s * kTS + lg * 4 + i;
                float* orow = out + ((size_t)(1 + t) * kBATCH + bglob + mtY) * kNY +
                              (w >> 1) * 32 + lw;
#pragma unroll
                for (int nt = 0; nt < 2; ++nt)
                    orow[nt * 16] = acc2[nt][i] + bias[nt];
            }
        }
    }

    if constexpr (!FINAL) {
        const size_t eb = ((size_t)c * kBATCH + bglob + bl) * kNH;
        ends[eb + hm]      = x1;
        ends[eb + hm + kH] = x2;
    }
}

// ---------------------------------------------------------------------------
// Sequential combine over chunks + x0 computation + FUSED Y row 0.
// lambda^256 = 8 squarings. x0 (= starts[c=0]) is resident as s1/s2 at c=0;
// share it through LDS, then 64 threads project Y[0] = Wx2y@x0 + bx2y.
// Replaces the separate y0_kernel (one less launch in the serial chain).
// ---------------------------------------------------------------------------
__global__ __launch_bounds__(128) void combine_kernel(
    const float* __restrict__ y0, const float* __restrict__ Wy2x,
    const float* __restrict__ by2x, const float* __restrict__ lre,
    const float* __restrict__ lim, const float* __restrict__ ends,
    const float* __restrict__ Wx2y, const float* __restrict__ bx2y,
    float* __restrict__ starts, float* __restrict__ out)
{
    __shared__ float x0sh[kNH];
    const int b  = blockIdx.x;
    const int hm = threadIdx.x;

    const float ab = fabsf(lre[hm]);
    const float r  = expf(-ab);
    const float th = 1.5707963267948966f * lim[hm];
    float lr = r * cosf(th);
    float li = r * sinf(th);
    float pr = lr, pi = li;
#pragma unroll
    for (int k = 0; k < 8; ++k) {  // lambda^256 (kCHUNK = 256 = 2^8)
        const float nr = pr * pr - pi * pi;
        const float ni = 2.0f * pr * pi;
        pr = nr; pi = ni;
    }

    float s1 = by2x[hm];
    float s2 = by2x[hm + kH];
#pragma unroll 8
    for (int q = 0; q < kNY; ++q) {
        const float yv = y0[b * kNY + q];
        s1 = fmaf(Wy2x[hm * kNY + q], yv, s1);
        s2 = fmaf(Wy2x[(hm + kH) * kNY + q], yv, s2);
    }

    // share x0 for the fused Y0 projection
    x0sh[hm]      = s1;
    x0sh[hm + kH] = s2;

    for (int c = 0; c < kNCHUNK; ++c) {
        const size_t base = ((size_t)c * kBATCH + b) * kNH;
        starts[base + hm]      = s1;
        starts[base + hm + kH] = s2;
        const float e1 = ends[base + hm];
        const float e2 = ends[base + hm + kH];
        const float n1 = fmaf(pr, s1, fmaf(-pi, s2, e1));
        const float n2 = fmaf(pi, s1, fmaf(pr, s2, e2));
        s1 = n1; s2 = n2;
    }

    __syncthreads();
    // Y[0][b] = Wx2y @ x0 + bx2y  (threads 0..63)
    if (hm < kNY) {
        float acc = bx2y[hm];
#pragma unroll 4
        for (int h = 0; h < kNH; h += 4) {
            float4 xv = *(const float4*)&x0sh[h];
            float4 wv = *(const float4*)&Wx2y[hm * kNH + h];
            acc = fmaf(wv.x, xv.x, acc);
            acc = fmaf(wv.y, xv.y, acc);
            acc = fmaf(wv.z, xv.z, acc);
            acc = fmaf(wv.w, xv.w, acc);
        }
        out[(size_t)b * kNY + hm] = acc;
    }
}

extern "C" void kernel_launch(void* const* d_in, const int* in_sizes, int n_in,
                              void* d_out, int out_size, void* d_ws, size_t ws_size,
                              hipStream_t stream) {
    const float* y0   = (const float*)d_in[0];
    const float* U    = (const float*)d_in[1];
    const float* lre  = (const float*)d_in[2];
    const float* lim  = (const float*)d_in[3];
    const float* Bmat = (const float*)d_in[4];
    const float* Wy2x = (const float*)d_in[5];
    const float* by2x = (const float*)d_in[6];
    const float* Wx2y = (const float*)d_in[7];
    const float* bx2y = (const float*)d_in[8];
    float* out = (float*)d_out;

    float* ends   = (float*)d_ws;                          // 1 MB
    float* starts = ends + (size_t)kNCHUNK * kBATCH * kNH; // 1 MB

    const int grid = kNCHUNK * (kBATCH / kBT);  // 512 blocks

    scan_mfma<false><<<grid, 256, SMEM1, stream>>>(
        U, lre, lim, Bmat, nullptr, nullptr, nullptr, ends, nullptr);
    combine_kernel<<<kBATCH, 128, 0, stream>>>(
        y0, Wy2x, by2x, lre, lim, ends, Wx2y, bx2y, starts, out);
    scan_mfma<true><<<grid, 256, SMEM2, stream>>>(
        U, lre, lim, Bmat, Wx2y, bx2y, starts, nullptr, out);
}